// Round 1
// 335.591 us; speedup vs baseline: 1.0039x; 1.0039x over previous
//
#include <hip/hip_runtime.h>

// DCTPolicy: coeffs = scatter(mean + exp(log_std)*eps), log_prob, entropy.
//
// R6 structure: wave-private strips, NO __syncthreads between load and store
// phases. Each block = 4 waves = 4 strips; wave w loads strip w (12 float4,
// 1 KiB/wave contiguous per instruction), stages samples into its OWN LDS
// region (intra-wave dep -> compiler lgkmcnt only, no barrier), then writes
// its 8x512 output strip (1 KiB/wave contiguous stores). Waves stream fully
// independently like a copy kernel. The single barrier sits AFTER stores are
// issued and gates only the partials write. Zigzag ranks are compile-time
// (q unrolled -> u=q>>1 uniform): 30 LDS reads/thread (was 64), rows 6-7 are
// pure zero stores. Param coverage & partials semantics identical to R4.

constexpr int W = 4096;
constexpr int H = 4096;
constexpr long long CHW = 3LL * 4096 * 4096;           // 50331648
constexpr float LOG2PI = 1.8378770664093453f;          // ln(2*pi)
constexpr int NBLK = 3072;                             // 4 strips per block
constexpr float NTOT = 12582912.0f;                    // C*NH*NW*K

// zigzag rank of (u,v) within an 8x8 block, 0xFF = not in first 16 coeffs.
constexpr unsigned char ZR[8][8] = {
    {0,    2,    3,    9,    10,   0xFF, 0xFF, 0xFF},
    {1,    4,    8,    11,   0xFF, 0xFF, 0xFF, 0xFF},
    {5,    7,    12,   0xFF, 0xFF, 0xFF, 0xFF, 0xFF},
    {6,    13,   0xFF, 0xFF, 0xFF, 0xFF, 0xFF, 0xFF},
    {14,   0xFF, 0xFF, 0xFF, 0xFF, 0xFF, 0xFF, 0xFF},
    {15,   0xFF, 0xFF, 0xFF, 0xFF, 0xFF, 0xFF, 0xFF},
    {0xFF, 0xFF, 0xFF, 0xFF, 0xFF, 0xFF, 0xFF, 0xFF},
    {0xFF, 0xFF, 0xFF, 0xFF, 0xFF, 0xFF, 0xFF, 0xFF}
};

__global__ __launch_bounds__(256) void dct_policy_kernel(
    const float* __restrict__ mean,
    const float* __restrict__ log_std,
    const float* __restrict__ eps,
    float* __restrict__ out,
    float2* __restrict__ partials)
{
    __shared__ float smp[4][64 * 17];   // 4 wave-private strips, stride-17 pad
    __shared__ float p1[4], p2[4];

    const int t   = threadIdx.x;        // 0..255
    const int w   = t >> 6;             // wave id == strip id 0..3
    const int ln  = t & 63;             // lane
    const int bid = blockIdx.x;         // 0..3071
    const int c   = bid >> 10;          // channel (1024 blocks per channel)
    const int rem = bid & 1023;
    const int bh  = rem >> 1;           // tile row 0..511
    const int hx  = rem & 1;            // which 2048-col half

    // ---- Phase 1: strip w's 12 float4 loads, all in flight, 1 KiB/wave/instr
    const long long pbase = (long long)(c * 512 + bh) * 8192
                          + (long long)hx * 4096 + (long long)w * 1024;

    float4 m4[4], l4[4], e4[4];
#pragma unroll
    for (int j = 0; j < 4; ++j) {
        const long long g = pbase + 256 * j + 4 * ln;
        m4[j] = *(const float4*)(mean    + g);
        l4[j] = *(const float4*)(log_std + g);
        e4[j] = *(const float4*)(eps     + g);
    }

    const int g0 = ln >> 2;             // tile sub-index within 16-tile group
    const int rb = (ln & 3) * 4;        // rank base within tile
    float s1 = 0.f, s2 = 0.f;
#pragma unroll
    for (int j = 0; j < 4; ++j) {
        const int tile = 16 * j + g0;
        const float mv[4] = {m4[j].x, m4[j].y, m4[j].z, m4[j].w};
        const float lv[4] = {l4[j].x, l4[j].y, l4[j].z, l4[j].w};
        const float ev[4] = {e4[j].x, e4[j].y, e4[j].z, e4[j].w};
#pragma unroll
        for (int i = 0; i < 4; ++i) {
            const float s = mv[i] + __builtin_expf(lv[i]) * ev[i]; // SCALE=1
            smp[w][tile * 17 + rb + i] = s;
            s1 += ev[i] * ev[i];
            s2 += lv[i];
        }
    }

#pragma unroll
    for (int off = 32; off > 0; off >>= 1) {
        s1 += __shfl_xor(s1, off, 64);
        s2 += __shfl_xor(s2, off, 64);
    }
    if (ln == 0) { p1[w] = s1; p2[w] = s2; }

    // ---- Phase 2: wave-private LDS -> global, NO barrier needed.
    // Wave reads only its own strip's LDS (compiler emits lgkmcnt).
    const long long obase = (long long)c * ((long long)H * W)
                          + (long long)(bh * 8) * W
                          + (long long)hx * 2048 + (long long)w * 512;
    const int par = ln & 1;             // even lanes: v=0..3, odd: v=4..7
#pragma unroll
    for (int q = 0; q < 16; ++q) {
        const int u  = q >> 1;                  // row, compile-time
        const int x4 = (q & 1) * 64 + ln;       // float4 col 0..127
        const int tl = x4 >> 1;                 // tile 0..63
        float4 o;
        float* ov = (float*)&o;
#pragma unroll
        for (int j = 0; j < 4; ++j) {
            const int re = ZR[u][j];            // compile-time constants
            const int ro = ZR[u][4 + j];
            if (re == 0xFF && ro == 0xFF) {
                ov[j] = 0.0f;
            } else {
                const int r = par ? ro : re;    // one side may be 0xFF
                const float v = smp[w][tl * 17 + (r & 15)];
                ov[j] = (r != 0xFF) ? v : 0.0f;
            }
        }
        *(float4*)(out + obase + (long long)u * W + (long long)x4 * 4) = o;
    }

    // Barrier only gates the tiny partials write; stores are already issued.
    __syncthreads();
    if (t == 0) {
        partials[bid] = make_float2(p1[0] + p1[1] + p1[2] + p1[3],
                                    p2[0] + p2[1] + p2[2] + p2[3]);
    }
}

__global__ __launch_bounds__(256) void reduce_kernel(
    const float2* __restrict__ partials,
    float* __restrict__ out)
{
    const int t = threadIdx.x;
    float s1 = 0.f, s2 = 0.f;
    for (int i = t; i < NBLK; i += 256) {
        const float2 v = partials[i];
        s1 += v.x;
        s2 += v.y;
    }
#pragma unroll
    for (int off = 32; off > 0; off >>= 1) {
        s1 += __shfl_xor(s1, off, 64);
        s2 += __shfl_xor(s2, off, 64);
    }
    __shared__ float a1[4], a2[4];
    if ((t & 63) == 0) { a1[t >> 6] = s1; a2[t >> 6] = s2; }
    __syncthreads();
    if (t == 0) {
        const float S1 = a1[0] + a1[1] + a1[2] + a1[3];  // sum eps^2
        const float S2 = a2[0] + a2[1] + a2[2] + a2[3];  // sum log_std
        out[CHW]     = -0.5f * S1 - S2 - 0.5f * NTOT * LOG2PI;
        out[CHW + 1] = 0.5f * (1.0f + LOG2PI) * NTOT + S2;
    }
}

extern "C" void kernel_launch(void* const* d_in, const int* in_sizes, int n_in,
                              void* d_out, int out_size, void* d_ws, size_t ws_size,
                              hipStream_t stream) {
    const float* mean    = (const float*)d_in[0];
    const float* log_std = (const float*)d_in[1];
    const float* eps     = (const float*)d_in[2];
    float* out = (float*)d_out;
    float2* partials = (float2*)d_ws;   // 3072 * 8 B = 24 KiB

    dct_policy_kernel<<<NBLK, 256, 0, stream>>>(mean, log_std, eps, out, partials);
    reduce_kernel<<<1, 256, 0, stream>>>(partials, out);
}